// Round 2
// baseline (434.527 us; speedup 1.0000x reference)
//
#include <hip/hip_runtime.h>
#include <hip/hip_bf16.h>

// Problem constants (from reference): B=64 groups, 100 nodes/group, H=64,
// K=5 label classes, A=50 actions/group, 3 GNN steps, 9900 edges/group.
// ALL float tensors are float32 (per reference setup_inputs); int tensors int32.
#define HD 64
#define NPG 100
#define NGRP 64
#define NACT 50
#define EPG 9900

typedef const float* fcp;

// ---------------------------------------------------------------------------
// K1: per (group, 25-destination chunk) block.
//  - builds Wt[g][j][i] = e1^2 * d   (dst-major; diagonal = 0)
//  - t4_sum[j][:] = sum_{i!=j} relu(d*e1 * t4_w + t4_b)   (register acc)
//  - base[n][:]  = label@l1_w + l1_b + t4_sum@t3_w + t3_b
//  - hA[n][:]    = relu(base + l2_b)          (GNN step 1 with h=0, exact)
// ---------------------------------------------------------------------------
__global__ __launch_bounds__(256)
void k_edge_base(fcp label, fcp e_type, fcp dvec,
                 fcp l1_w, fcp l1_b, fcp l2_b,
                 fcp t3_w, fcp t3_b, fcp t4_w, fcp t4_b,
                 float* __restrict__ Wt, float* __restrict__ baseo,
                 float* __restrict__ hA)
{
    const int g  = blockIdx.x >> 2;
    const int c  = blockIdx.x & 3;
    const int t  = threadIdx.x;
    const int hh = t & 63;
    const int jw = t >> 6;          // wave id 0..3 (one j per wave per round)

    __shared__ float t4s[25 * HD];

    const float w4 = t4_w[hh];
    const float b4 = t4_b[hh];
    const int ebase = g * EPG;

    for (int jl = jw; jl < 25; jl += 4) {
        const int j = c * 25 + jl;
        const int wrow = g * (NPG * NPG) + j * NPG;
        float acc = 0.f;
        for (int i = 0; i < NPG; ++i) {
            if (i == j) {
                if (hh == 0) Wt[wrow + i] = 0.f;   // diagonal (no self-edge)
                continue;
            }
            const int e = ebase + i * 99 + j - (j > i ? 1 : 0);
            const float e1 = e_type[2 * e];
            const float dd = dvec[e];
            acc += fmaxf(dd * e1 * w4 + b4, 0.f);
            if (hh == 0) Wt[wrow + i] = e1 * e1 * dd;
        }
        t4s[jl * HD + hh] = acc;
    }
    __syncthreads();

    const float l1b = l1_b[hh];
    const float t3b = t3_b[hh];
    const float l2b = l2_b[hh];
    for (int jl = jw; jl < 25; jl += 4) {
        const int j = c * 25 + jl;
        const int n = g * NPG + j;
        float v = l1b + t3b;
        #pragma unroll
        for (int k = 0; k < 5; ++k)
            v += label[n * 5 + k] * l1_w[k * HD + hh];
        #pragma unroll 8
        for (int q = 0; q < HD; ++q)
            v += t4s[jl * HD + q] * t3_w[q * HD + hh];
        baseo[n * HD + hh] = v;
        hA[n * HD + hh]    = fmaxf(v + l2b, 0.f);   // step 1 (n1_h == 0)
    }
}

// ---------------------------------------------------------------------------
// K2: one GNN step. Block = (group, 25-destination chunk).
//   phase 1: n1[j][:] = sum_i Wt[g][j][i] * h[i][:]   (h slab in LDS)
//   phase 2: h'[j][:] = relu(base[j][:] + n1[j][:]@l2_w + l2_b)
// ---------------------------------------------------------------------------
__global__ __launch_bounds__(256)
void k_gnn_step(const float* __restrict__ Wt, const float* __restrict__ baseo,
                const float* __restrict__ h_old, fcp l2_w, fcp l2_b,
                float* __restrict__ h_new)
{
    const int g  = blockIdx.x >> 2;
    const int c  = blockIdx.x & 3;
    const int t  = threadIdx.x;
    const int hh = t & 63;
    const int jw = t >> 6;

    __shared__ float hs[NPG * HD];     // 25.6 KB
    __shared__ float n1s[25 * HD];     // 6.4 KB

    const float* hg = h_old + g * NPG * HD;
    for (int idx = t; idx < NPG * HD; idx += 256) hs[idx] = hg[idx];
    __syncthreads();

    for (int jl = jw; jl < 25; jl += 4) {
        const int j = c * 25 + jl;
        const float* wrow = Wt + g * (NPG * NPG) + j * NPG;
        float acc = 0.f;
        #pragma unroll 4
        for (int i = 0; i < NPG; ++i)
            acc += wrow[i] * hs[i * HD + hh];
        n1s[jl * HD + hh] = acc;
    }
    __syncthreads();

    const float l2b = l2_b[hh];
    for (int jl = jw; jl < 25; jl += 4) {
        const int j = c * 25 + jl;
        const int n = g * NPG + j;
        float v = baseo[n * HD + hh] + l2b;
        #pragma unroll 8
        for (int q = 0; q < HD; ++q)
            v += n1s[jl * HD + q] * l2_w[q * HD + hh];
        h_new[n * HD + hh] = fmaxf(v, 0.f);
    }
}

// ---------------------------------------------------------------------------
// K3: tail. One block per group.
//   stem = mean_j(h) @ t6_w + t6_b ; g_branch = relu(stem)@t9_1_w + t9_1_b
//   per action: ha = (h[a0]+h[a1])@t7_1_w + 2*t7_1_b  (== h2[a0]+h2[a1])
//               r1 = relu(ha); r2 = relu(r1@t7_2_w + t7_2_b)
//               u  = r2@t9_2_w + t9_2_b ; q = relu(g_branch + u)
//               Q  = q . t5_w + t5_b[0]   (wave64 butterfly reduce)
// ---------------------------------------------------------------------------
__global__ __launch_bounds__(256)
void k_tail(const float* __restrict__ hfin, const int* __restrict__ actions,
            fcp t5_w, fcp t5_b, fcp t6_w, fcp t6_b,
            fcp t7_1_w, fcp t7_1_b, fcp t7_2_w, fcp t7_2_b,
            fcp t9_1_w, fcp t9_1_b, fcp t9_2_w, fcp t9_2_b,
            float* __restrict__ out)
{
    const int g  = blockIdx.x;
    const int t  = threadIdx.x;
    const int hh = t & 63;
    const int aw = t >> 6;

    __shared__ float hsb[NPG * HD];      // 25.6 KB
    __shared__ float hsum[NACT * HD];    // 12.8 KB (reused as r2)
    __shared__ float r1[NACT * HD];      // 12.8 KB
    __shared__ float meanl[HD];
    __shared__ float srelu[HD];
    __shared__ float gb[HD];

    const float* hg = hfin + g * NPG * HD;
    for (int idx = t; idx < NPG * HD; idx += 256) hsb[idx] = hg[idx];
    __syncthreads();

    if (t < HD) {
        float m = 0.f;
        for (int j = 0; j < NPG; ++j) m += hsb[j * HD + t];
        meanl[t] = m * (1.f / NPG);
    }
    __syncthreads();
    if (t < HD) {
        float s = t6_b[t];
        for (int q = 0; q < HD; ++q) s += meanl[q] * t6_w[q * HD + t];
        srelu[t] = fmaxf(s, 0.f);
    }
    __syncthreads();
    if (t < HD) {
        float s = t9_1_b[t];
        for (int q = 0; q < HD; ++q) s += srelu[q] * t9_1_w[q * HD + t];
        gb[t] = s;
    }
    // hsum = h[a0] + h[a1]  (local node indices, 0..99)
    for (int a = aw; a < NACT; a += 4) {
        const int a0 = actions[(g * NACT + a) * 2 + 0];
        const int a1 = actions[(g * NACT + a) * 2 + 1];
        hsum[a * HD + hh] = hsb[a0 * HD + hh] + hsb[a1 * HD + hh];
    }
    __syncthreads();   // also covers gb[] writes above

    const float b71 = 2.f * t7_1_b[hh];
    for (int a = aw; a < NACT; a += 4) {
        float v = b71;
        #pragma unroll 8
        for (int q = 0; q < HD; ++q) v += hsum[a * HD + q] * t7_1_w[q * HD + hh];
        r1[a * HD + hh] = fmaxf(v, 0.f);
    }
    __syncthreads();

    const float b72 = t7_2_b[hh];
    for (int a = aw; a < NACT; a += 4) {
        float v = b72;
        #pragma unroll 8
        for (int q = 0; q < HD; ++q) v += r1[a * HD + q] * t7_2_w[q * HD + hh];
        hsum[a * HD + hh] = fmaxf(v, 0.f);   // r2 overwrites hsum (sync'd)
    }
    __syncthreads();

    const float b92 = t9_2_b[hh];
    const float t5w = t5_w[hh];
    const float t5b = t5_b[0];
    for (int a = aw; a < NACT; a += 4) {
        float v = b92;
        #pragma unroll 8
        for (int q = 0; q < HD; ++q) v += hsum[a * HD + q] * t9_2_w[q * HD + hh];
        float qv = fmaxf(gb[hh] + v, 0.f) * t5w;
        #pragma unroll
        for (int off = 32; off > 0; off >>= 1) qv += __shfl_xor(qv, off, 64);
        if (hh == 0) out[g * NACT + a] = qv + t5b;
    }
}

// ---------------------------------------------------------------------------
extern "C" void kernel_launch(void* const* d_in, const int* in_sizes, int n_in,
                              void* d_out, int out_size, void* d_ws, size_t ws_size,
                              hipStream_t stream)
{
    fcp label  = (fcp)d_in[0];
    fcp e_type = (fcp)d_in[1];
    fcp dvec   = (fcp)d_in[2];
    fcp l1_w   = (fcp)d_in[3];
    fcp l1_b   = (fcp)d_in[4];
    fcp l2_w   = (fcp)d_in[5];
    fcp l2_b   = (fcp)d_in[6];
    fcp t3_w   = (fcp)d_in[7];
    fcp t3_b   = (fcp)d_in[8];
    fcp t4_w   = (fcp)d_in[9];
    fcp t4_b   = (fcp)d_in[10];
    fcp t5_w   = (fcp)d_in[11];
    fcp t5_b   = (fcp)d_in[12];
    fcp t6_w   = (fcp)d_in[13];
    fcp t6_b   = (fcp)d_in[14];
    fcp t7_1_w = (fcp)d_in[15];
    fcp t7_1_b = (fcp)d_in[16];
    fcp t7_2_w = (fcp)d_in[17];
    fcp t7_2_b = (fcp)d_in[18];
    fcp t9_1_w = (fcp)d_in[19];
    fcp t9_1_b = (fcp)d_in[20];
    fcp t9_2_w = (fcp)d_in[21];
    fcp t9_2_b = (fcp)d_in[22];
    // d_in[23] = src, d_in[24] = dst  -- edge topology derived analytically
    const int* actions = (const int*)d_in[25];

    // Workspace layout (7,475,200 B total):
    //   Wt   : 64*100*100 f32 = 2,560,000
    //   base : 64*100*64  f32 = 1,638,400
    //   hA   : 1,638,400     hB : 1,638,400
    char* ws = (char*)d_ws;
    float* Wt   = (float*)(ws);
    float* base = (float*)(ws + 2560000);
    float* hA   = (float*)(ws + 2560000 + 1638400);
    float* hB   = (float*)(ws + 2560000 + 2 * 1638400);

    k_edge_base<<<dim3(NGRP * 4), dim3(256), 0, stream>>>(
        label, e_type, dvec, l1_w, l1_b, l2_b, t3_w, t3_b, t4_w, t4_b,
        Wt, base, hA);
    // GNN steps 2 and 3 (step 1 folded into k_edge_base since h0 = 0)
    k_gnn_step<<<dim3(NGRP * 4), dim3(256), 0, stream>>>(Wt, base, hA, l2_w, l2_b, hB);
    k_gnn_step<<<dim3(NGRP * 4), dim3(256), 0, stream>>>(Wt, base, hB, l2_w, l2_b, hA);
    k_tail<<<dim3(NGRP), dim3(256), 0, stream>>>(
        hA, actions, t5_w, t5_b, t6_w, t6_b, t7_1_w, t7_1_b, t7_2_w, t7_2_b,
        t9_1_w, t9_1_b, t9_2_w, t9_2_b, (float*)d_out);
}

// Round 3
// 236.991 us; speedup vs baseline: 1.8335x; 1.8335x over previous
//
#include <hip/hip_runtime.h>
#include <hip/hip_bf16.h>

// Problem constants (from reference): B=64 groups, 100 nodes/group, H=64,
// K=5 label classes, A=50 actions/group, 3 GNN steps, 9900 edges/group.
// ALL float tensors are float32; int tensors int32.
#define HD 64
#define NPG 100
#define NGRP 64
#define NACT 50
#define EPG 9900

typedef const float* fcp;

// ---------------------------------------------------------------------------
// K1: block = (group, 25-destination chunk).  Grid 256.
// Phase A: coalesced-stage s_e = d*e1 and w_e = e1^2*d for all (i, j in chunk)
//          into LDS, layout [jl][i] (diagonal staged as 0).
// Phase B: t4s[jl][h] = sum_i relu(s*w4+b4) - relu(b4)   (LDS broadcasts)
// Phase C: Wt[g][j][i] <- w_ld  (straight coalesced LDS->global copy)
// Phase D: base = label@l1_w + l1_b + t4s@t3_w + t3_b ; hA = relu(base+l2_b)
//          (GNN step 1 folded exactly since h0 = 0)
// ---------------------------------------------------------------------------
__global__ __launch_bounds__(256)
void k_edge_base(fcp label, fcp e_type, fcp dvec,
                 fcp l1_w, fcp l1_b, fcp l2_b,
                 fcp t3_w, fcp t3_b, fcp t4_w, fcp t4_b,
                 float* __restrict__ Wt, float* __restrict__ baseo,
                 float* __restrict__ hA)
{
    const int g  = blockIdx.x >> 2;
    const int c  = blockIdx.x & 3;
    const int t  = threadIdx.x;
    const int hh = t & 63;
    const int jw = t >> 6;          // wave id 0..3

    __shared__ float s_ld[25 * NPG];   // 10 KB
    __shared__ float w_ld[25 * NPG];   // 10 KB
    __shared__ float t4s[25 * HD];     // 6.4 KB

    const int ebase = g * EPG;
    const int j0 = c * 25;

    // Phase A: coalesced edge staging (j-fast so consecutive t -> consecutive e)
    for (int idx = t; idx < 25 * NPG; idx += 256) {
        const int i  = idx / 25;
        const int jl = idx % 25;
        const int j  = j0 + jl;
        float s = 0.f, w = 0.f;
        if (i != j) {
            const int e  = ebase + i * 99 + j - (j > i ? 1 : 0);
            const float e1 = e_type[2 * e];
            const float dd = dvec[e];
            s = dd * e1;
            w = e1 * e1 * dd;
        }
        s_ld[jl * NPG + i] = s;
        w_ld[jl * NPG + i] = w;
    }
    __syncthreads();

    // Phase B: t4 segment-sum per destination (all reads LDS broadcast)
    const float w4  = t4_w[hh];
    const float b4  = t4_b[hh];
    const float rb4 = fmaxf(b4, 0.f);          // spurious diagonal term
    for (int jl = jw; jl < 25; jl += 4) {
        float acc = -rb4;
        #pragma unroll 4
        for (int i = 0; i < NPG; ++i)
            acc += fmaxf(s_ld[jl * NPG + i] * w4 + b4, 0.f);
        t4s[jl * HD + hh] = acc;
    }

    // Phase C: Wt write (coalesced; layout matches [j][i] with j = j0+jl)
    {
        float* wdst = Wt + g * (NPG * NPG) + c * 2500;
        for (int idx = t; idx < 2500; idx += 256) wdst[idx] = w_ld[idx];
    }
    __syncthreads();

    // Phase D: base + folded step 1
    const float l1b = l1_b[hh];
    const float t3b = t3_b[hh];
    const float l2b = l2_b[hh];
    for (int jl = jw; jl < 25; jl += 4) {
        const int n = g * NPG + j0 + jl;
        float v = l1b + t3b;
        #pragma unroll
        for (int k = 0; k < 5; ++k)
            v += label[n * 5 + k] * l1_w[k * HD + hh];
        #pragma unroll 8
        for (int q = 0; q < HD; ++q)
            v += t4s[jl * HD + q] * t3_w[q * HD + hh];
        baseo[n * HD + hh] = v;
        hA[n * HD + hh]    = fmaxf(v + l2b, 0.f);
    }
}

// ---------------------------------------------------------------------------
// K2: one GNN step. Block = (group, 25-destination chunk). Grid 256.
//   stage h slab (25.6 KB) + Wt chunk (10 KB) into LDS coalesced;
//   phase 1: n1[j][:] = sum_i Wt[j][i] * h[i][:]  (7 accumulators/lane,
//            one hs read per i, Wt via LDS broadcast)
//   phase 2: h' = relu(base + n1@l2_w + l2_b)
// ---------------------------------------------------------------------------
__global__ __launch_bounds__(256)
void k_gnn_step(const float* __restrict__ Wt, const float* __restrict__ baseo,
                const float* __restrict__ h_old, fcp l2_w, fcp l2_b,
                float* __restrict__ h_new)
{
    const int g  = blockIdx.x >> 2;
    const int c  = blockIdx.x & 3;
    const int t  = threadIdx.x;
    const int hh = t & 63;
    const int jw = t >> 6;

    __shared__ float hs[NPG * HD];     // 25.6 KB
    __shared__ float wr[25 * NPG];     // 10 KB
    __shared__ float n1s[25 * HD];     // 6.4 KB

    const float* hg = h_old + g * NPG * HD;
    for (int idx = t; idx < NPG * HD; idx += 256) hs[idx] = hg[idx];
    const float* wsrc = Wt + g * (NPG * NPG) + c * 2500;
    for (int idx = t; idx < 2500; idx += 256) wr[idx] = wsrc[idx];
    __syncthreads();

    // Phase 1: each wave owns jl in {jw, jw+4, ...} (7 slots max)
    {
        float acc[7];
        #pragma unroll
        for (int k = 0; k < 7; ++k) acc[k] = 0.f;
        for (int i = 0; i < NPG; ++i) {
            const float hv = hs[i * HD + hh];
            #pragma unroll
            for (int k = 0; k < 7; ++k) {
                const int jl = jw + 4 * k;
                if (jl < 25) acc[k] += wr[jl * NPG + i] * hv;
            }
        }
        #pragma unroll
        for (int k = 0; k < 7; ++k) {
            const int jl = jw + 4 * k;
            if (jl < 25) n1s[jl * HD + hh] = acc[k];
        }
    }
    __syncthreads();

    // Phase 2
    const float l2b = l2_b[hh];
    for (int jl = jw; jl < 25; jl += 4) {
        const int n = g * NPG + c * 25 + jl;
        float v = baseo[n * HD + hh] + l2b;
        #pragma unroll 8
        for (int q = 0; q < HD; ++q)
            v += n1s[jl * HD + q] * l2_w[q * HD + hh];
        h_new[n * HD + hh] = fmaxf(v, 0.f);
    }
}

// ---------------------------------------------------------------------------
// K3: tail. Block = (group, half of the 50 actions). Grid 128.
//   stem = mean_j(h)@t6_w + t6_b ; gb = relu(stem)@t9_1_w + t9_1_b
//   per action: ha = (h[a0]+h[a1])@t7_1_w + 2*t7_1_b  (== h2[a0]+h2[a1])
//               r1 = relu(ha); r2 = relu(r1@t7_2_w + t7_2_b)
//               u  = r2@t9_2_w + t9_2_b ; q = relu(gb + u)
//               Q  = q . t5_w + t5_b[0]   (wave64 butterfly reduce)
// ---------------------------------------------------------------------------
__global__ __launch_bounds__(256)
void k_tail(const float* __restrict__ hfin, const int* __restrict__ actions,
            fcp t5_w, fcp t5_b, fcp t6_w, fcp t6_b,
            fcp t7_1_w, fcp t7_1_b, fcp t7_2_w, fcp t7_2_b,
            fcp t9_1_w, fcp t9_1_b, fcp t9_2_w, fcp t9_2_b,
            float* __restrict__ out)
{
    const int g    = blockIdx.x >> 1;
    const int half = blockIdx.x & 1;
    const int t    = threadIdx.x;
    const int hh   = t & 63;
    const int aw   = t >> 6;

    __shared__ float hsb[NPG * HD];      // 25.6 KB
    __shared__ float hsum[25 * HD];      // 6.4 KB (reused as r2)
    __shared__ float r1[25 * HD];        // 6.4 KB
    __shared__ float mpart[4][HD];
    __shared__ float meanl[HD];
    __shared__ float srelu[HD];
    __shared__ float gb[HD];

    const float* hg = hfin + g * NPG * HD;
    for (int idx = t; idx < NPG * HD; idx += 256) hsb[idx] = hg[idx];
    __syncthreads();

    // mean over the 100 nodes: 4 partial sums (one per wave), then combine
    {
        float m = 0.f;
        for (int j = aw * 25; j < aw * 25 + 25; ++j) m += hsb[j * HD + hh];
        mpart[aw][hh] = m;
    }
    __syncthreads();
    if (t < HD)
        meanl[t] = (mpart[0][t] + mpart[1][t] + mpart[2][t] + mpart[3][t]) * (1.f / NPG);
    __syncthreads();
    if (t < HD) {
        float s = t6_b[t];
        #pragma unroll 8
        for (int q = 0; q < HD; ++q) s += meanl[q] * t6_w[q * HD + t];
        srelu[t] = fmaxf(s, 0.f);
    }
    __syncthreads();
    if (t < HD) {
        float s = t9_1_b[t];
        #pragma unroll 8
        for (int q = 0; q < HD; ++q) s += srelu[q] * t9_1_w[q * HD + t];
        gb[t] = s;
    }

    const int a0g = half * 25;                 // this block's action range
    // hsum = h[a0] + h[a1]  (local LDS index al = a - a0g)
    for (int al = aw; al < 25; al += 4) {
        const int a  = a0g + al;
        const int i0 = actions[(g * NACT + a) * 2 + 0];
        const int i1 = actions[(g * NACT + a) * 2 + 1];
        hsum[al * HD + hh] = hsb[i0 * HD + hh] + hsb[i1 * HD + hh];
    }
    __syncthreads();   // also covers gb[] writes

    const float b71 = 2.f * t7_1_b[hh];
    for (int al = aw; al < 25; al += 4) {
        float v = b71;
        #pragma unroll 8
        for (int q = 0; q < HD; ++q) v += hsum[al * HD + q] * t7_1_w[q * HD + hh];
        r1[al * HD + hh] = fmaxf(v, 0.f);
    }
    __syncthreads();

    const float b72 = t7_2_b[hh];
    for (int al = aw; al < 25; al += 4) {
        float v = b72;
        #pragma unroll 8
        for (int q = 0; q < HD; ++q) v += r1[al * HD + q] * t7_2_w[q * HD + hh];
        hsum[al * HD + hh] = fmaxf(v, 0.f);    // r2 overwrites hsum (sync'd)
    }
    __syncthreads();

    const float b92 = t9_2_b[hh];
    const float t5w = t5_w[hh];
    const float t5b = t5_b[0];
    for (int al = aw; al < 25; al += 4) {
        float v = b92;
        #pragma unroll 8
        for (int q = 0; q < HD; ++q) v += hsum[al * HD + q] * t9_2_w[q * HD + hh];
        float qv = fmaxf(gb[hh] + v, 0.f) * t5w;
        #pragma unroll
        for (int off = 32; off > 0; off >>= 1) qv += __shfl_xor(qv, off, 64);
        if (hh == 0) out[g * NACT + a0g + al] = qv + t5b;
    }
}

// ---------------------------------------------------------------------------
extern "C" void kernel_launch(void* const* d_in, const int* in_sizes, int n_in,
                              void* d_out, int out_size, void* d_ws, size_t ws_size,
                              hipStream_t stream)
{
    fcp label  = (fcp)d_in[0];
    fcp e_type = (fcp)d_in[1];
    fcp dvec   = (fcp)d_in[2];
    fcp l1_w   = (fcp)d_in[3];
    fcp l1_b   = (fcp)d_in[4];
    fcp l2_w   = (fcp)d_in[5];
    fcp l2_b   = (fcp)d_in[6];
    fcp t3_w   = (fcp)d_in[7];
    fcp t3_b   = (fcp)d_in[8];
    fcp t4_w   = (fcp)d_in[9];
    fcp t4_b   = (fcp)d_in[10];
    fcp t5_w   = (fcp)d_in[11];
    fcp t5_b   = (fcp)d_in[12];
    fcp t6_w   = (fcp)d_in[13];
    fcp t6_b   = (fcp)d_in[14];
    fcp t7_1_w = (fcp)d_in[15];
    fcp t7_1_b = (fcp)d_in[16];
    fcp t7_2_w = (fcp)d_in[17];
    fcp t7_2_b = (fcp)d_in[18];
    fcp t9_1_w = (fcp)d_in[19];
    fcp t9_1_b = (fcp)d_in[20];
    fcp t9_2_w = (fcp)d_in[21];
    fcp t9_2_b = (fcp)d_in[22];
    // d_in[23] = src, d_in[24] = dst  -- edge topology derived analytically
    const int* actions = (const int*)d_in[25];

    // Workspace layout:
    //   Wt   : 64*100*100 f32 = 2,560,000 B
    //   base : 64*100*64  f32 = 1,638,400 B
    //   hA, hB : 1,638,400 B each
    char* ws = (char*)d_ws;
    float* Wt   = (float*)(ws);
    float* base = (float*)(ws + 2560000);
    float* hA   = (float*)(ws + 2560000 + 1638400);
    float* hB   = (float*)(ws + 2560000 + 2 * 1638400);

    k_edge_base<<<dim3(NGRP * 4), dim3(256), 0, stream>>>(
        label, e_type, dvec, l1_w, l1_b, l2_b, t3_w, t3_b, t4_w, t4_b,
        Wt, base, hA);
    // GNN steps 2 and 3 (step 1 folded into k_edge_base since h0 = 0)
    k_gnn_step<<<dim3(NGRP * 4), dim3(256), 0, stream>>>(Wt, base, hA, l2_w, l2_b, hB);
    k_gnn_step<<<dim3(NGRP * 4), dim3(256), 0, stream>>>(Wt, base, hB, l2_w, l2_b, hA);
    k_tail<<<dim3(NGRP * 2), dim3(256), 0, stream>>>(
        hA, actions, t5_w, t5_b, t6_w, t6_b, t7_1_w, t7_1_b, t7_2_w, t7_2_b,
        t9_1_w, t9_1_b, t9_2_w, t9_2_b, (float*)d_out);
}